// Round 1
// baseline (5178.542 us; speedup 1.0000x reference)
//
#include <hip/hip_runtime.h>
#include <math.h>

#define IN_DIM 128
#define HID 64
#define HEADS 4
#define NEG_SLOPE 0.2f
#define LN_EPS 1e-5f

// ---------- edge dtype detection (int64 vs int32) ----------
__global__ void k_flag_init(int* flag) {
    if (blockIdx.x == 0 && threadIdx.x == 0) *flag = 1;
}

// Read first E int64-words (always in-bounds: buffer is at least 2E*4 bytes).
// If data really is int64, these are edge_index[0] values, all in [0,n).
// If data is int32, each word packs two random node ids -> value >= n almost surely.
__global__ void k_detect(const unsigned long long* ei, int count, int n, int* flag) {
    int i = blockIdx.x * blockDim.x + threadIdx.x;
    if (i < count) {
        if (ei[i] >= (unsigned long long)n) atomicAnd(flag, 0);
    }
}

__global__ void k_remap(const void* ei, int twoE, const int* flag, int* edges32) {
    int i = blockIdx.x * blockDim.x + threadIdx.x;
    if (i >= twoE) return;
    int is64 = *flag;
    long long v;
    if (is64) v = ((const long long*)ei)[i];
    else      v = (long long)((const int*)ei)[i];
    edges32[i] = (int)v;
}

// ---------- init accumulators (ws is poisoned 0xAA every launch) ----------
__global__ void k_init(float* deg, unsigned* m_u, float* denom, float* agg, int n) {
    int i = blockIdx.x * blockDim.x + threadIdx.x;
    if (i < n) deg[i] = 1.0f;                 // self-loop contributes 1
    if (i < n * HEADS) { m_u[i] = 0u; denom[i] = 0.0f; }
    if (i < n * HID) agg[i] = 0.0f;
}

__global__ void k_deg(const int* dst, float* deg, int E) {
    int i = blockIdx.x * blockDim.x + threadIdx.x;
    if (i < E) atomicAdd(&deg[dst[i]], 1.0f);
}

__global__ void k_dinv(float* deg, int n) {
    int i = blockIdx.x * blockDim.x + threadIdx.x;
    if (i < n) deg[i] = rsqrtf(deg[i]);       // deg>=1 always (self-loop)
}

// ---------- xw = x @ W_gcn : [n,128]@[128,64] ----------
__global__ __launch_bounds__(256) void k_xw(const float* __restrict__ x,
                                            const float* __restrict__ W,
                                            float* __restrict__ xw, int n) {
    __shared__ float Wl[IN_DIM * HID];   // 32 KB
    __shared__ float xl[4 * IN_DIM];     // 2 KB
    int t = threadIdx.x;
    for (int i = t; i < IN_DIM * HID; i += 256) Wl[i] = W[i];
    int row0 = blockIdx.x * 4;
    for (int i = t; i < 4 * IN_DIM; i += 256) {
        int r = row0 + i / IN_DIM;
        xl[i] = (r < n) ? x[(size_t)r * IN_DIM + (i % IN_DIM)] : 0.0f;
    }
    __syncthreads();
    int c = t & 63, r = t >> 6;
    float acc = 0.0f;
    for (int k = 0; k < IN_DIM; k++) acc += xl[r * IN_DIM + k] * Wl[k * HID + c];
    int rr = row0 + r;
    if (rr < n) xw[(size_t)rr * HID + c] = acc;
}

// ---------- h1 init with self-loop term: xw * dinv^2 ----------
__global__ void k_h1_init(const float* __restrict__ xw, const float* __restrict__ dinv,
                          float* __restrict__ h1, int n) {
    int i = blockIdx.x * blockDim.x + threadIdx.x;
    if (i < n * HID) {
        int r = i >> 6;
        float dv = dinv[r];
        h1[i] = xw[i] * dv * dv;
    }
}

// ---------- GCN scatter-add: one wave per edge ----------
__global__ __launch_bounds__(256) void k_gcn_scatter(const int* __restrict__ src,
                                                     const int* __restrict__ dst,
                                                     const float* __restrict__ dinv,
                                                     const float* __restrict__ xw,
                                                     float* __restrict__ h1, int E) {
    int e = blockIdx.x * 4 + (threadIdx.x >> 6);
    int c = threadIdx.x & 63;
    if (e >= E) return;
    int s = src[e], d = dst[e];
    float nm = dinv[s] * dinv[d];
    atomicAdd(&h1[(size_t)d * HID + c], xw[(size_t)s * HID + c] * nm);
}

__global__ void k_relu_bias(float* h1, const float* __restrict__ b, int n) {
    int i = blockIdx.x * blockDim.x + threadIdx.x;
    if (i < n * HID) h1[i] = fmaxf(h1[i] + b[i & 63], 0.0f);
}

// ---------- z = h1 @ W_gat [n,64]@[64,256], fused a_src/a_dst reductions ----------
// grid: (ceil(n/16), HEADS). block 256: wave w handles local rows {w*?..}, c=lane
__global__ __launch_bounds__(256) void k_zgemm(const float* __restrict__ h1,
                                               const float* __restrict__ Wg,
                                               const float* __restrict__ att_s,
                                               const float* __restrict__ att_d,
                                               float* __restrict__ z,
                                               float* __restrict__ a_s,
                                               float* __restrict__ a_d, int n) {
    __shared__ float Wl[HID * 64];   // 16 KB (this head's 64 columns)
    __shared__ float hl[16 * HID];   // 4 KB
    int hh = blockIdx.y;
    int t = threadIdx.x, c = t & 63, r2 = t >> 6;
    for (int i = t; i < HID * 64; i += 256) {
        int k = i >> 6, cc = i & 63;
        Wl[i] = Wg[(size_t)k * (HEADS * HID) + hh * 64 + cc];
    }
    int row0 = blockIdx.x * 16;
    for (int i = t; i < 16 * HID; i += 256) {
        int r = row0 + (i >> 6);
        hl[i] = (r < n) ? h1[(size_t)r * HID + (i & 63)] : 0.0f;
    }
    __syncthreads();
    float as_c = att_s[hh * 64 + c], ad_c = att_d[hh * 64 + c];
    for (int j = 0; j < 4; j++) {
        int rl = r2 * 4 + j;
        float acc = 0.0f;
        for (int k = 0; k < HID; k++) acc += hl[rl * HID + k] * Wl[k * 64 + c];
        int r = row0 + rl;
        if (r < n) z[(size_t)r * (HEADS * HID) + hh * 64 + c] = acc;
        float vs = acc * as_c, vd = acc * ad_c;
        for (int o = 32; o > 0; o >>= 1) {
            vs += __shfl_xor(vs, o, 64);
            vd += __shfl_xor(vd, o, 64);
        }
        if (c == 0 && r < n) { a_s[r * HEADS + hh] = vs; a_d[r * HEADS + hh] = vd; }
    }
}

// ---------- attention: monotone float<->uint for atomicMax ----------
__device__ inline unsigned fenc(float x) {
    unsigned u = __float_as_uint(x);
    return (u & 0x80000000u) ? ~u : (u | 0x80000000u);
}
__device__ inline float fdec(unsigned u) {
    return (u & 0x80000000u) ? __uint_as_float(u & 0x7fffffffu) : __uint_as_float(~u);
}

// pass 1: e = leaky_relu(a_s[src]+a_d[dst]); store; segment max
__global__ void k_att1(const int* __restrict__ src, const int* __restrict__ dst,
                       const float* __restrict__ a_s, const float* __restrict__ a_d,
                       float* __restrict__ e_buf, unsigned* __restrict__ m_u,
                       int E, int n) {
    int idx = blockIdx.x * blockDim.x + threadIdx.x;
    int tot = (E + n) * HEADS;
    if (idx >= tot) return;
    int e = idx >> 2, h = idx & 3;
    int s, d;
    if (e < E) { s = src[e]; d = dst[e]; } else { s = d = e - E; }
    float v = a_s[s * HEADS + h] + a_d[d * HEADS + h];
    v = (v > 0.0f) ? v : NEG_SLOPE * v;
    e_buf[idx] = v;
    atomicMax(&m_u[d * HEADS + h], fenc(v));
}

// pass 2: ex = exp(e - m[dst]); store; segment sum
__global__ void k_att2(const int* __restrict__ src, const int* __restrict__ dst,
                       const unsigned* __restrict__ m_u, float* __restrict__ e_buf,
                       float* __restrict__ denom, int E, int n) {
    int idx = blockIdx.x * blockDim.x + threadIdx.x;
    int tot = (E + n) * HEADS;
    if (idx >= tot) return;
    int e = idx >> 2, h = idx & 3;
    int d = (e < E) ? dst[e] : (e - E);
    float ex = expf(e_buf[idx] - fdec(m_u[d * HEADS + h]));
    e_buf[idx] = ex;
    atomicAdd(&denom[d * HEADS + h], ex);
}

// pass 3: agg[d,c] += sum_h alpha_h * z[s,h,c]  (head-sum fused per edge)
__global__ __launch_bounds__(256) void k_att3(const int* __restrict__ src,
                                              const int* __restrict__ dst,
                                              const float* __restrict__ e_buf,
                                              const float* __restrict__ denom,
                                              const float* __restrict__ z,
                                              float* __restrict__ agg, int E, int n) {
    int e = blockIdx.x * 4 + (threadIdx.x >> 6);
    int c = threadIdx.x & 63;
    if (e >= E + n) return;
    int s, d;
    if (e < E) { s = src[e]; d = dst[e]; } else { s = d = e - E; }
    float v = 0.0f;
    const float* zr = z + (size_t)s * (HEADS * HID);
#pragma unroll
    for (int h = 0; h < HEADS; h++) {
        float alpha = e_buf[e * HEADS + h] / denom[d * HEADS + h];
        v += alpha * zr[h * HID + c];
    }
    atomicAdd(&agg[(size_t)d * HID + c], v);
}

// ---------- epilogue: h_patch matvec + residual + LayerNorm, one wave/node ----------
__global__ __launch_bounds__(256) void k_final(const float* __restrict__ h1,
                                               const float* __restrict__ agg,
                                               const float* __restrict__ Wp,
                                               const float* __restrict__ bp,
                                               const float* __restrict__ bg,
                                               const float* __restrict__ gamma,
                                               const float* __restrict__ beta,
                                               float* __restrict__ out, int n) {
    __shared__ float Wl[HID * HID];  // 16 KB
    int t = threadIdx.x;
    for (int i = t; i < HID * HID; i += 256) Wl[i] = Wp[i];
    __syncthreads();
    int c = t & 63;
    int r = blockIdx.x * 4 + (t >> 6);
    if (r >= n) return;
    float h1c = h1[(size_t)r * HID + c];
    float hp = bp[c];
    for (int k = 0; k < HID; k++) hp += __shfl(h1c, k, 64) * Wl[k * HID + c];
    float h2 = fmaxf(agg[(size_t)r * HID + c] * 0.25f + bg[c], 0.0f);
    float h = h1c + h2 + hp;
    float s1 = h, s2 = h * h;
    for (int o = 32; o > 0; o >>= 1) {
        s1 += __shfl_xor(s1, o, 64);
        s2 += __shfl_xor(s2, o, 64);
    }
    float mu = s1 * (1.0f / 64.0f);
    float var = s2 * (1.0f / 64.0f) - mu * mu;
    out[(size_t)r * HID + c] = (h - mu) * rsqrtf(var + LN_EPS) * gamma[c] + beta[c];
}

extern "C" void kernel_launch(void* const* d_in, const int* in_sizes, int n_in,
                              void* d_out, int out_size, void* d_ws, size_t ws_size,
                              hipStream_t stream) {
    int n = in_sizes[0] / IN_DIM;
    int E = in_sizes[1] / 2;

    const float* x     = (const float*)d_in[0];
    const void*  ei    = d_in[1];
    const float* W_gcn = (const float*)d_in[2];
    const float* b_gcn = (const float*)d_in[3];
    const float* W_gat = (const float*)d_in[4];
    const float* att_s = (const float*)d_in[5];
    const float* att_d = (const float*)d_in[6];
    const float* b_gat = (const float*)d_in[7];
    const float* W_p   = (const float*)d_in[8];
    const float* b_p   = (const float*)d_in[9];
    const float* gamma = (const float*)d_in[10];
    const float* beta  = (const float*)d_in[11];

    float* ws = (float*)d_ws;
    size_t off = 0;
    int*      flag   = (int*)(ws + off);      off += 1;
    int*      edges  = (int*)(ws + off);      off += (size_t)2 * E;
    float*    dinv   = ws + off;              off += n;           // deg then dinv in-place
    float*    xw     = ws + off;              off += (size_t)n * HID;
    float*    h1     = ws + off;              off += (size_t)n * HID;
    float*    z      = ws + off;              off += (size_t)n * HEADS * HID;
    float*    a_sv   = ws + off;              off += (size_t)n * HEADS;
    float*    a_dv   = ws + off;              off += (size_t)n * HEADS;
    unsigned* m_u    = (unsigned*)(ws + off); off += (size_t)n * HEADS;
    float*    denom  = ws + off;              off += (size_t)n * HEADS;
    float*    agg    = ws + off;              off += (size_t)n * HID;
    float*    e_buf  = ws + off;              off += (size_t)(E + n) * HEADS;

    const int* src = edges;
    const int* dst = edges + E;

    int nb;
    // dtype detect + remap edge_index to int32
    k_flag_init<<<1, 64, 0, stream>>>(flag);
    nb = (E + 255) / 256;
    k_detect<<<nb, 256, 0, stream>>>((const unsigned long long*)ei, E, n, flag);
    nb = (2 * E + 255) / 256;
    k_remap<<<nb, 256, 0, stream>>>(ei, 2 * E, flag, edges);

    // init accumulators
    nb = (n * HID + 255) / 256;
    k_init<<<nb, 256, 0, stream>>>(dinv, m_u, denom, agg, n);

    // degree + norm
    nb = (E + 255) / 256;
    k_deg<<<nb, 256, 0, stream>>>(dst, dinv, E);
    nb = (n + 255) / 256;
    k_dinv<<<nb, 256, 0, stream>>>(dinv, n);

    // GCN
    k_xw<<<(n + 3) / 4, 256, 0, stream>>>(x, W_gcn, xw, n);
    nb = (n * HID + 255) / 256;
    k_h1_init<<<nb, 256, 0, stream>>>(xw, dinv, h1, n);
    k_gcn_scatter<<<(E + 3) / 4, 256, 0, stream>>>(src, dst, dinv, xw, h1, E);
    k_relu_bias<<<nb, 256, 0, stream>>>(h1, b_gcn, n);

    // GAT projections + attention logits
    dim3 zg((n + 15) / 16, HEADS);
    k_zgemm<<<zg, 256, 0, stream>>>(h1, W_gat, att_s, att_d, z, a_sv, a_dv, n);

    int tot = (E + n) * HEADS;
    nb = (tot + 255) / 256;
    k_att1<<<nb, 256, 0, stream>>>(src, dst, a_sv, a_dv, e_buf, m_u, E, n);
    k_att2<<<nb, 256, 0, stream>>>(src, dst, m_u, e_buf, denom, E, n);
    k_att3<<<(E + n + 3) / 4, 256, 0, stream>>>(src, dst, e_buf, denom, z, agg, E, n);

    // epilogue
    k_final<<<(n + 3) / 4, 256, 0, stream>>>(h1, agg, W_p, b_p, b_gat, gamma, beta,
                                             (float*)d_out, n);
}

// Round 2
// 628.126 us; speedup vs baseline: 8.2444x; 8.2444x over previous
//
#include <hip/hip_runtime.h>
#include <math.h>

#define IN_DIM 128
#define HID 64
#define HEADS 4
#define NEG_SLOPE 0.2f
#define LN_EPS 1e-5f

// ---------- edge dtype detection (int64 vs int32), sampled ----------
// Single block samples first 4096 u64 words. If data is int32, each word packs
// two random node ids -> high word nonzero with p=1-2e-5 -> value >= n.
// P(miss over 4096 samples) ~ (2e-5)^4096 = 0. Writes flag exactly once.
__global__ void k_detect(const unsigned long long* ei, int count, int n, int* flag) {
    __shared__ int s_bad;
    if (threadIdx.x == 0) s_bad = 0;
    __syncthreads();
    int lim = count < 4096 ? count : 4096;
    int bad = 0;
    for (int i = threadIdx.x; i < lim; i += 256)
        if (ei[i] >= (unsigned long long)n) bad = 1;
    if (bad) s_bad = 1;          // benign race
    __syncthreads();
    if (threadIdx.x == 0) *flag = s_bad ? 0 : 1;   // 1 = genuine int64
}

__global__ void k_remap(const void* ei, int twoE, const int* flag, int* edges32) {
    int i = blockIdx.x * blockDim.x + threadIdx.x;
    if (i >= twoE) return;
    int is64 = *flag;
    long long v;
    if (is64) v = ((const long long*)ei)[i];
    else      v = (long long)((const int*)ei)[i];
    edges32[i] = (int)v;
}

// ---------- init accumulators (ws is poisoned 0xAA every launch) ----------
__global__ void k_init(float* deg, unsigned* m_u, float* denom, float* agg, int n) {
    int i = blockIdx.x * blockDim.x + threadIdx.x;
    if (i < n) deg[i] = 1.0f;                 // self-loop contributes 1
    if (i < n * HEADS) { m_u[i] = 0u; denom[i] = 0.0f; }
    if (i < n * HID) agg[i] = 0.0f;
}

__global__ void k_deg(const int* dst, float* deg, int E) {
    int i = blockIdx.x * blockDim.x + threadIdx.x;
    if (i < E) atomicAdd(&deg[dst[i]], 1.0f);
}

__global__ void k_dinv(float* deg, int n) {
    int i = blockIdx.x * blockDim.x + threadIdx.x;
    if (i < n) deg[i] = rsqrtf(deg[i]);       // deg>=1 always (self-loop)
}

// ---------- xw = x @ W_gcn : [n,128]@[128,64] ----------
__global__ __launch_bounds__(256) void k_xw(const float* __restrict__ x,
                                            const float* __restrict__ W,
                                            float* __restrict__ xw, int n) {
    __shared__ float Wl[IN_DIM * HID];   // 32 KB
    __shared__ float xl[4 * IN_DIM];     // 2 KB
    int t = threadIdx.x;
    for (int i = t; i < IN_DIM * HID; i += 256) Wl[i] = W[i];
    int row0 = blockIdx.x * 4;
    for (int i = t; i < 4 * IN_DIM; i += 256) {
        int r = row0 + i / IN_DIM;
        xl[i] = (r < n) ? x[(size_t)r * IN_DIM + (i % IN_DIM)] : 0.0f;
    }
    __syncthreads();
    int c = t & 63, r = t >> 6;
    float acc = 0.0f;
    for (int k = 0; k < IN_DIM; k++) acc += xl[r * IN_DIM + k] * Wl[k * HID + c];
    int rr = row0 + r;
    if (rr < n) xw[(size_t)rr * HID + c] = acc;
}

// ---------- h1 init with self-loop term: xw * dinv^2 ----------
__global__ void k_h1_init(const float* __restrict__ xw, const float* __restrict__ dinv,
                          float* __restrict__ h1, int n) {
    int i = blockIdx.x * blockDim.x + threadIdx.x;
    if (i < n * HID) {
        int r = i >> 6;
        float dv = dinv[r];
        h1[i] = xw[i] * dv * dv;
    }
}

// ---------- GCN scatter-add: one wave per edge ----------
__global__ __launch_bounds__(256) void k_gcn_scatter(const int* __restrict__ src,
                                                     const int* __restrict__ dst,
                                                     const float* __restrict__ dinv,
                                                     const float* __restrict__ xw,
                                                     float* __restrict__ h1, int E) {
    int e = blockIdx.x * 4 + (threadIdx.x >> 6);
    int c = threadIdx.x & 63;
    if (e >= E) return;
    int s = src[e], d = dst[e];
    float nm = dinv[s] * dinv[d];
    atomicAdd(&h1[(size_t)d * HID + c], xw[(size_t)s * HID + c] * nm);
}

__global__ void k_relu_bias(float* h1, const float* __restrict__ b, int n) {
    int i = blockIdx.x * blockDim.x + threadIdx.x;
    if (i < n * HID) h1[i] = fmaxf(h1[i] + b[i & 63], 0.0f);
}

// ---------- z = h1 @ W_gat [n,64]@[64,256], fused a_src/a_dst reductions ----------
__global__ __launch_bounds__(256) void k_zgemm(const float* __restrict__ h1,
                                               const float* __restrict__ Wg,
                                               const float* __restrict__ att_s,
                                               const float* __restrict__ att_d,
                                               float* __restrict__ z,
                                               float* __restrict__ a_s,
                                               float* __restrict__ a_d, int n) {
    __shared__ float Wl[HID * 64];   // 16 KB (this head's 64 columns)
    __shared__ float hl[16 * HID];   // 4 KB
    int hh = blockIdx.y;
    int t = threadIdx.x, c = t & 63, r2 = t >> 6;
    for (int i = t; i < HID * 64; i += 256) {
        int k = i >> 6, cc = i & 63;
        Wl[i] = Wg[(size_t)k * (HEADS * HID) + hh * 64 + cc];
    }
    int row0 = blockIdx.x * 16;
    for (int i = t; i < 16 * HID; i += 256) {
        int r = row0 + (i >> 6);
        hl[i] = (r < n) ? h1[(size_t)r * HID + (i & 63)] : 0.0f;
    }
    __syncthreads();
    float as_c = att_s[hh * 64 + c], ad_c = att_d[hh * 64 + c];
    for (int j = 0; j < 4; j++) {
        int rl = r2 * 4 + j;
        float acc = 0.0f;
        for (int k = 0; k < HID; k++) acc += hl[rl * HID + k] * Wl[k * 64 + c];
        int r = row0 + rl;
        if (r < n) z[(size_t)r * (HEADS * HID) + hh * 64 + c] = acc;
        float vs = acc * as_c, vd = acc * ad_c;
        for (int o = 32; o > 0; o >>= 1) {
            vs += __shfl_xor(vs, o, 64);
            vd += __shfl_xor(vd, o, 64);
        }
        if (c == 0 && r < n) { a_s[r * HEADS + hh] = vs; a_d[r * HEADS + hh] = vd; }
    }
}

// ---------- attention: monotone float<->uint for atomicMax ----------
__device__ inline unsigned fenc(float x) {
    unsigned u = __float_as_uint(x);
    return (u & 0x80000000u) ? ~u : (u | 0x80000000u);
}
__device__ inline float fdec(unsigned u) {
    return (u & 0x80000000u) ? __uint_as_float(u & 0x7fffffffu) : __uint_as_float(~u);
}

// pass 1: e = leaky_relu(a_s[src]+a_d[dst]); store; segment max
__global__ void k_att1(const int* __restrict__ src, const int* __restrict__ dst,
                       const float* __restrict__ a_s, const float* __restrict__ a_d,
                       float* __restrict__ e_buf, unsigned* __restrict__ m_u,
                       int E, int n) {
    int idx = blockIdx.x * blockDim.x + threadIdx.x;
    int tot = (E + n) * HEADS;
    if (idx >= tot) return;
    int e = idx >> 2, h = idx & 3;
    int s, d;
    if (e < E) { s = src[e]; d = dst[e]; } else { s = d = e - E; }
    float v = a_s[s * HEADS + h] + a_d[d * HEADS + h];
    v = (v > 0.0f) ? v : NEG_SLOPE * v;
    e_buf[idx] = v;
    atomicMax(&m_u[d * HEADS + h], fenc(v));
}

// pass 2: ex = exp(e - m[dst]); store; segment sum
__global__ void k_att2(const int* __restrict__ src, const int* __restrict__ dst,
                       const unsigned* __restrict__ m_u, float* __restrict__ e_buf,
                       float* __restrict__ denom, int E, int n) {
    int idx = blockIdx.x * blockDim.x + threadIdx.x;
    int tot = (E + n) * HEADS;
    if (idx >= tot) return;
    int e = idx >> 2, h = idx & 3;
    int d = (e < E) ? dst[e] : (e - E);
    float ex = expf(e_buf[idx] - fdec(m_u[d * HEADS + h]));
    e_buf[idx] = ex;
    atomicAdd(&denom[d * HEADS + h], ex);
}

// pass 3: agg[d,c] += sum_h alpha_h * z[s,h,c]  (head-sum fused per edge)
__global__ __launch_bounds__(256) void k_att3(const int* __restrict__ src,
                                              const int* __restrict__ dst,
                                              const float* __restrict__ e_buf,
                                              const float* __restrict__ denom,
                                              const float* __restrict__ z,
                                              float* __restrict__ agg, int E, int n) {
    int e = blockIdx.x * 4 + (threadIdx.x >> 6);
    int c = threadIdx.x & 63;
    if (e >= E + n) return;
    int s, d;
    if (e < E) { s = src[e]; d = dst[e]; } else { s = d = e - E; }
    float v = 0.0f;
    const float* zr = z + (size_t)s * (HEADS * HID);
#pragma unroll
    for (int h = 0; h < HEADS; h++) {
        float alpha = e_buf[e * HEADS + h] / denom[d * HEADS + h];
        v += alpha * zr[h * HID + c];
    }
    atomicAdd(&agg[(size_t)d * HID + c], v);
}

// ---------- epilogue: h_patch matvec + residual + LayerNorm, one wave/node ----------
__global__ __launch_bounds__(256) void k_final(const float* __restrict__ h1,
                                               const float* __restrict__ agg,
                                               const float* __restrict__ Wp,
                                               const float* __restrict__ bp,
                                               const float* __restrict__ bg,
                                               const float* __restrict__ gamma,
                                               const float* __restrict__ beta,
                                               float* __restrict__ out, int n) {
    __shared__ float Wl[HID * HID];  // 16 KB
    int t = threadIdx.x;
    for (int i = t; i < HID * HID; i += 256) Wl[i] = Wp[i];
    __syncthreads();
    int c = t & 63;
    int r = blockIdx.x * 4 + (t >> 6);
    if (r >= n) return;
    float h1c = h1[(size_t)r * HID + c];
    float hp = bp[c];
    for (int k = 0; k < HID; k++) hp += __shfl(h1c, k, 64) * Wl[k * HID + c];
    float h2 = fmaxf(agg[(size_t)r * HID + c] * 0.25f + bg[c], 0.0f);
    float h = h1c + h2 + hp;
    float s1 = h, s2 = h * h;
    for (int o = 32; o > 0; o >>= 1) {
        s1 += __shfl_xor(s1, o, 64);
        s2 += __shfl_xor(s2, o, 64);
    }
    float mu = s1 * (1.0f / 64.0f);
    float var = s2 * (1.0f / 64.0f) - mu * mu;
    out[(size_t)r * HID + c] = (h - mu) * rsqrtf(var + LN_EPS) * gamma[c] + beta[c];
}

extern "C" void kernel_launch(void* const* d_in, const int* in_sizes, int n_in,
                              void* d_out, int out_size, void* d_ws, size_t ws_size,
                              hipStream_t stream) {
    int n = in_sizes[0] / IN_DIM;
    int E = in_sizes[1] / 2;

    const float* x     = (const float*)d_in[0];
    const void*  ei    = d_in[1];
    const float* W_gcn = (const float*)d_in[2];
    const float* b_gcn = (const float*)d_in[3];
    const float* W_gat = (const float*)d_in[4];
    const float* att_s = (const float*)d_in[5];
    const float* att_d = (const float*)d_in[6];
    const float* b_gat = (const float*)d_in[7];
    const float* W_p   = (const float*)d_in[8];
    const float* b_p   = (const float*)d_in[9];
    const float* gamma = (const float*)d_in[10];
    const float* beta  = (const float*)d_in[11];

    float* ws = (float*)d_ws;
    size_t off = 0;
    int*      flag   = (int*)(ws + off);      off += 1;
    int*      edges  = (int*)(ws + off);      off += (size_t)2 * E;
    float*    dinv   = ws + off;              off += n;           // deg then dinv in-place
    float*    xw     = ws + off;              off += (size_t)n * HID;
    float*    h1     = ws + off;              off += (size_t)n * HID;
    float*    z      = ws + off;              off += (size_t)n * HEADS * HID;
    float*    a_sv   = ws + off;              off += (size_t)n * HEADS;
    float*    a_dv   = ws + off;              off += (size_t)n * HEADS;
    unsigned* m_u    = (unsigned*)(ws + off); off += (size_t)n * HEADS;
    float*    denom  = ws + off;              off += (size_t)n * HEADS;
    float*    agg    = ws + off;              off += (size_t)n * HID;
    float*    e_buf  = ws + off;              off += (size_t)(E + n) * HEADS;

    const int* src = edges;
    const int* dst = edges + E;

    int nb;
    // dtype detect (sampled, single block) + remap edge_index to int32
    k_detect<<<1, 256, 0, stream>>>((const unsigned long long*)ei, E, n, flag);
    nb = (2 * E + 255) / 256;
    k_remap<<<nb, 256, 0, stream>>>(ei, 2 * E, flag, edges);

    // init accumulators
    nb = (n * HID + 255) / 256;
    k_init<<<nb, 256, 0, stream>>>(dinv, m_u, denom, agg, n);

    // degree + norm
    nb = (E + 255) / 256;
    k_deg<<<nb, 256, 0, stream>>>(dst, dinv, E);
    nb = (n + 255) / 256;
    k_dinv<<<nb, 256, 0, stream>>>(dinv, n);

    // GCN
    k_xw<<<(n + 3) / 4, 256, 0, stream>>>(x, W_gcn, xw, n);
    nb = (n * HID + 255) / 256;
    k_h1_init<<<nb, 256, 0, stream>>>(xw, dinv, h1, n);
    k_gcn_scatter<<<(E + 3) / 4, 256, 0, stream>>>(src, dst, dinv, xw, h1, E);
    k_relu_bias<<<nb, 256, 0, stream>>>(h1, b_gcn, n);

    // GAT projections + attention logits
    dim3 zg((n + 15) / 16, HEADS);
    k_zgemm<<<zg, 256, 0, stream>>>(h1, W_gat, att_s, att_d, z, a_sv, a_dv, n);

    int tot = (E + n) * HEADS;
    nb = (tot + 255) / 256;
    k_att1<<<nb, 256, 0, stream>>>(src, dst, a_sv, a_dv, e_buf, m_u, E, n);
    k_att2<<<nb, 256, 0, stream>>>(src, dst, m_u, e_buf, denom, E, n);
    k_att3<<<(E + n + 3) / 4, 256, 0, stream>>>(src, dst, e_buf, denom, z, agg, E, n);

    // epilogue
    k_final<<<(n + 3) / 4, 256, 0, stream>>>(h1, agg, W_p, b_p, b_gat, gamma, beta,
                                             (float*)d_out, n);
}

// Round 3
// 431.542 us; speedup vs baseline: 12.0001x; 1.4555x over previous
//
#include <hip/hip_runtime.h>
#include <math.h>

#define IN_DIM 128
#define HID 64
#define HEADS 4
#define NEG_SLOPE 0.2f
#define LN_EPS 1e-5f

// ---------- edge dtype detection (int64 vs int32), sampled ----------
__global__ void k_detect(const unsigned long long* ei, int count, int n, int* flag) {
    __shared__ int s_bad;
    if (threadIdx.x == 0) s_bad = 0;
    __syncthreads();
    int lim = count < 4096 ? count : 4096;
    int bad = 0;
    for (int i = threadIdx.x; i < lim; i += 256)
        if (ei[i] >= (unsigned long long)n) bad = 1;
    if (bad) s_bad = 1;          // benign race
    __syncthreads();
    if (threadIdx.x == 0) *flag = s_bad ? 0 : 1;   // 1 = genuine int64
}

__global__ void k_remap(const void* ei, int twoE, const int* flag, int* edges32) {
    int i = blockIdx.x * blockDim.x + threadIdx.x;
    if (i >= twoE) return;
    int is64 = *flag;
    long long v;
    if (is64) v = ((const long long*)ei)[i];
    else      v = (long long)((const int*)ei)[i];
    edges32[i] = (int)v;
}

// ---------- CSR build: hist -> scan -> scatter ----------
__global__ void k_zero(int* hist, int n) {
    int i = blockIdx.x * blockDim.x + threadIdx.x;
    if (i < n) hist[i] = 0;
}

__global__ void k_hist(const int* __restrict__ dst, int* __restrict__ hist, int E) {
    int i = blockIdx.x * blockDim.x + threadIdx.x;
    if (i < E) atomicAdd(&hist[dst[i]], 1);
}

// block-local exclusive scan; tmp[i] = local exclusive, partial[b] = block sum
__global__ __launch_bounds__(256) void k_scan1(const int* __restrict__ hist,
                                               int* __restrict__ tmp,
                                               int* __restrict__ partial, int n) {
    __shared__ int s[256];
    int t = threadIdx.x, i = blockIdx.x * 256 + t;
    int v = (i < n) ? hist[i] : 0;
    s[t] = v;
    __syncthreads();
    for (int off = 1; off < 256; off <<= 1) {
        int x = (t >= off) ? s[t - off] : 0;
        __syncthreads();
        s[t] += x;
        __syncthreads();
    }
    tmp[i] = s[t] - v;
    if (t == 255) partial[blockIdx.x] = s[255];
}

// scan of block sums (assumes nblocks <= 256)
__global__ __launch_bounds__(256) void k_scan2(int* partial, int nb) {
    __shared__ int s[256];
    int t = threadIdx.x;
    int v = (t < nb) ? partial[t] : 0;
    s[t] = v;
    __syncthreads();
    for (int off = 1; off < 256; off <<= 1) {
        int x = (t >= off) ? s[t - off] : 0;
        __syncthreads();
        s[t] += x;
        __syncthreads();
    }
    if (t < nb) partial[t] = s[t] - v;
}

__global__ void k_scan3(const int* __restrict__ tmp, const int* __restrict__ partial,
                        const int* __restrict__ hist, int* __restrict__ row_ptr,
                        int* __restrict__ cursor, float* __restrict__ dinv, int n) {
    int i = blockIdx.x * blockDim.x + threadIdx.x;
    if (i >= n) return;
    int v = tmp[i] + partial[blockIdx.x * 256 / 256 == 0 ? 0 : 0];  // placeholder (fixed below)
    v = tmp[i] + partial[i >> 8];
    row_ptr[i] = v;
    cursor[i] = v;
    dinv[i] = rsqrtf((float)(hist[i] + 1));   // +1 self-loop
}

__global__ void k_scatter(const int* __restrict__ src, const int* __restrict__ dst,
                          int* __restrict__ cursor, int* __restrict__ col, int E) {
    int i = blockIdx.x * blockDim.x + threadIdx.x;
    if (i >= E) return;
    int pos = atomicAdd(&cursor[dst[i]], 1);
    col[pos] = src[i];
}

// ---------- fold att vectors through W_gat: w_s[h,k] = sum_c Wg[k,h,c]*att_s[h,c] ----------
__global__ void k_prep(const float* __restrict__ Wg, const float* __restrict__ att_s,
                       const float* __restrict__ att_d, float* __restrict__ w_s,
                       float* __restrict__ w_d) {
    int t = threadIdx.x;            // 256 threads: h = t>>6, k = t&63
    int h = t >> 6, k = t & 63;
    float ss = 0.0f, sd = 0.0f;
    for (int c = 0; c < HID; c++) {
        float w = Wg[(size_t)k * (HEADS * HID) + h * HID + c];
        ss += w * att_s[h * HID + c];
        sd += w * att_d[h * HID + c];
    }
    w_s[h * HID + k] = ss;
    w_d[h * HID + k] = sd;
}

// ---------- xw = x @ W_gcn : [n,128]@[128,64], 16 rows/block ----------
__global__ __launch_bounds__(256) void k_xw(const float* __restrict__ x,
                                            const float* __restrict__ W,
                                            float* __restrict__ xw, int n) {
    __shared__ float Wl[IN_DIM * HID];   // 32 KB
    __shared__ float xl[16 * IN_DIM];    // 8 KB
    int t = threadIdx.x;
    for (int i = t; i < IN_DIM * HID; i += 256) Wl[i] = W[i];
    int row0 = blockIdx.x * 16;
    for (int i = t; i < 16 * IN_DIM; i += 256) {
        int r = row0 + (i >> 7);
        xl[i] = (r < n) ? x[(size_t)r * IN_DIM + (i & 127)] : 0.0f;
    }
    __syncthreads();
    int c = t & 63, w = t >> 6;
    for (int j = 0; j < 4; j++) {
        int rl = w * 4 + j;
        float acc = 0.0f;
        for (int k = 0; k < IN_DIM; k++) acc += xl[rl * IN_DIM + k] * Wl[k * HID + c];
        int r = row0 + rl;
        if (r < n) xw[(size_t)r * HID + c] = acc;
    }
}

// ---------- GCN via CSR gather + fused bias/relu + attention-logit dots ----------
__global__ __launch_bounds__(256) void k_gcn(const int* __restrict__ col,
                                             const int* __restrict__ row_ptr,
                                             const int* __restrict__ hist,
                                             const float* __restrict__ dinv,
                                             const float* __restrict__ xw,
                                             const float* __restrict__ b,
                                             const float* __restrict__ w_s,
                                             const float* __restrict__ w_d,
                                             float* __restrict__ h1,
                                             float* __restrict__ a_s,
                                             float* __restrict__ a_d, int n) {
    int t = threadIdx.x, c = t & 63;
    int d = blockIdx.x * 4 + (t >> 6);
    if (d >= n) return;
    int start = row_ptr[d], cnt = hist[d];
    float acc = 0.0f;
    for (int k = 0; k < cnt; k++) {
        int s = col[start + k];
        acc += xw[(size_t)s * HID + c] * dinv[s];
    }
    float dd = dinv[d];
    float h1c = fmaxf((acc + xw[(size_t)d * HID + c] * dd) * dd + b[c], 0.0f);
    h1[(size_t)d * HID + c] = h1c;
    // a_s[d,h] = sum_c h1c * w_s[h,c]   (4 heads x 2) via butterfly
    float vs0 = h1c * w_s[c],           vs1 = h1c * w_s[64 + c];
    float vs2 = h1c * w_s[128 + c],     vs3 = h1c * w_s[192 + c];
    float vd0 = h1c * w_d[c],           vd1 = h1c * w_d[64 + c];
    float vd2 = h1c * w_d[128 + c],     vd3 = h1c * w_d[192 + c];
    for (int o = 32; o > 0; o >>= 1) {
        vs0 += __shfl_xor(vs0, o, 64); vs1 += __shfl_xor(vs1, o, 64);
        vs2 += __shfl_xor(vs2, o, 64); vs3 += __shfl_xor(vs3, o, 64);
        vd0 += __shfl_xor(vd0, o, 64); vd1 += __shfl_xor(vd1, o, 64);
        vd2 += __shfl_xor(vd2, o, 64); vd3 += __shfl_xor(vd3, o, 64);
    }
    if (c == 0) {
        a_s[d * 4 + 0] = vs0; a_s[d * 4 + 1] = vs1;
        a_s[d * 4 + 2] = vs2; a_s[d * 4 + 3] = vs3;
        a_d[d * 4 + 0] = vd0; a_d[d * 4 + 1] = vd1;
        a_d[d * 4 + 2] = vd2; a_d[d * 4 + 3] = vd3;
    }
}

// ---------- z = h1 @ W_gat  (pure GEMM, 64 rows/block per head) ----------
__global__ __launch_bounds__(256) void k_zgemm(const float* __restrict__ h1,
                                               const float* __restrict__ Wg,
                                               float* __restrict__ z, int n) {
    __shared__ float Wl[HID * 64];   // 16 KB
    __shared__ float hl[64 * HID];   // 16 KB
    int hh = blockIdx.y;
    int t = threadIdx.x, c = t & 63, w = t >> 6;
    for (int i = t; i < HID * 64; i += 256) {
        int k = i >> 6, cc = i & 63;
        Wl[i] = Wg[(size_t)k * (HEADS * HID) + hh * 64 + cc];
    }
    int row0 = blockIdx.x * 64;
    for (int i = t; i < 64 * HID; i += 256) {
        int r = row0 + (i >> 6);
        hl[i] = (r < n) ? h1[(size_t)r * HID + (i & 63)] : 0.0f;
    }
    __syncthreads();
    for (int j = 0; j < 16; j++) {
        int rl = w * 16 + j;
        float acc = 0.0f;
        for (int k = 0; k < HID; k++) acc += hl[rl * HID + k] * Wl[k * 64 + c];
        int r = row0 + rl;
        if (r < n) z[(size_t)r * (HEADS * HID) + hh * 64 + c] = acc;
    }
}

__device__ inline float leaky(float v) { return v > 0.0f ? v : NEG_SLOPE * v; }

// ---------- fused: online-softmax GAT agg + W_patch matvec + residual + LN ----------
__global__ __launch_bounds__(256) void k_attn(const int* __restrict__ col,
                                              const int* __restrict__ row_ptr,
                                              const int* __restrict__ hist,
                                              const float* __restrict__ a_s,
                                              const float* __restrict__ a_d,
                                              const float* __restrict__ z,
                                              const float* __restrict__ h1,
                                              const float* __restrict__ Wp,
                                              const float* __restrict__ bp,
                                              const float* __restrict__ bg,
                                              const float* __restrict__ gamma,
                                              const float* __restrict__ beta,
                                              float* __restrict__ out, int n) {
    __shared__ float Wl[HID * HID];  // 16 KB
    int t = threadIdx.x;
    for (int i = t; i < HID * HID; i += 256) Wl[i] = Wp[i];
    __syncthreads();
    int c = t & 63;
    int d = blockIdx.x * 4 + (t >> 6);
    if (d >= n) return;
    float ad0 = a_d[d * 4 + 0], ad1 = a_d[d * 4 + 1];
    float ad2 = a_d[d * 4 + 2], ad3 = a_d[d * 4 + 3];
    // init with self edge (always present)
    float m0 = leaky(a_s[d * 4 + 0] + ad0), m1 = leaky(a_s[d * 4 + 1] + ad1);
    float m2 = leaky(a_s[d * 4 + 2] + ad2), m3 = leaky(a_s[d * 4 + 3] + ad3);
    float l0 = 1.0f, l1 = 1.0f, l2 = 1.0f, l3 = 1.0f;
    const float* zd = z + (size_t)d * (HEADS * HID);
    float A0 = zd[c], A1 = zd[64 + c], A2 = zd[128 + c], A3 = zd[192 + c];
    int start = row_ptr[d], cnt = hist[d];
    for (int k = 0; k < cnt; k++) {
        int s = col[start + k];
        const float* zs = z + (size_t)s * (HEADS * HID);
        float e0 = leaky(a_s[s * 4 + 0] + ad0);
        float e1 = leaky(a_s[s * 4 + 1] + ad1);
        float e2 = leaky(a_s[s * 4 + 2] + ad2);
        float e3 = leaky(a_s[s * 4 + 3] + ad3);
        float z0 = zs[c], z1 = zs[64 + c], z2 = zs[128 + c], z3 = zs[192 + c];
        float nm, sc, w;
        nm = fmaxf(m0, e0); sc = __expf(m0 - nm); w = __expf(e0 - nm);
        l0 = l0 * sc + w; A0 = A0 * sc + w * z0; m0 = nm;
        nm = fmaxf(m1, e1); sc = __expf(m1 - nm); w = __expf(e1 - nm);
        l1 = l1 * sc + w; A1 = A1 * sc + w * z1; m1 = nm;
        nm = fmaxf(m2, e2); sc = __expf(m2 - nm); w = __expf(e2 - nm);
        l2 = l2 * sc + w; A2 = A2 * sc + w * z2; m2 = nm;
        nm = fmaxf(m3, e3); sc = __expf(m3 - nm); w = __expf(e3 - nm);
        l3 = l3 * sc + w; A3 = A3 * sc + w * z3; m3 = nm;
    }
    float v = A0 / l0 + A1 / l1 + A2 / l2 + A3 / l3;
    float h2 = fmaxf(0.25f * v + bg[c], 0.0f);
    float h1c = h1[(size_t)d * HID + c];
    float hp = bp[c];
    for (int k = 0; k < HID; k++) hp += __shfl(h1c, k, 64) * Wl[k * HID + c];
    float h = h1c + h2 + hp;
    float s1 = h, s2 = h * h;
    for (int o = 32; o > 0; o >>= 1) {
        s1 += __shfl_xor(s1, o, 64);
        s2 += __shfl_xor(s2, o, 64);
    }
    float mu = s1 * (1.0f / 64.0f);
    float var = s2 * (1.0f / 64.0f) - mu * mu;
    out[(size_t)d * HID + c] = (h - mu) * rsqrtf(var + LN_EPS) * gamma[c] + beta[c];
}

extern "C" void kernel_launch(void* const* d_in, const int* in_sizes, int n_in,
                              void* d_out, int out_size, void* d_ws, size_t ws_size,
                              hipStream_t stream) {
    int n = in_sizes[0] / IN_DIM;
    int E = in_sizes[1] / 2;

    const float* x     = (const float*)d_in[0];
    const void*  ei    = d_in[1];
    const float* W_gcn = (const float*)d_in[2];
    const float* b_gcn = (const float*)d_in[3];
    const float* W_gat = (const float*)d_in[4];
    const float* att_s = (const float*)d_in[5];
    const float* att_d = (const float*)d_in[6];
    const float* b_gat = (const float*)d_in[7];
    const float* W_p   = (const float*)d_in[8];
    const float* b_p   = (const float*)d_in[9];
    const float* gamma = (const float*)d_in[10];
    const float* beta  = (const float*)d_in[11];

    int n_pad = ((n + 255) / 256) * 256;
    int nscan = n_pad / 256;                 // 196 for n=50000 (must be <= 256)

    float* ws = (float*)d_ws;
    size_t off = 0;
    int*   flag    = (int*)(ws + off);  off += 1;
    int*   edges   = (int*)(ws + off);  off += (size_t)2 * E;
    int*   hist    = (int*)(ws + off);  off += n;
    int*   row_ptr = (int*)(ws + off);  off += n;
    int*   cursor  = (int*)(ws + off);  off += n;
    int*   tmp     = (int*)(ws + off);  off += n_pad;
    int*   partial = (int*)(ws + off);  off += 256;
    int*   colv    = (int*)(ws + off);  off += E;
    float* dinv    = ws + off;          off += n;
    float* w_s     = ws + off;          off += HEADS * HID;
    float* w_d     = ws + off;          off += HEADS * HID;
    float* xw      = ws + off;          off += (size_t)n * HID;
    float* h1      = ws + off;          off += (size_t)n * HID;
    float* a_sv    = ws + off;          off += (size_t)n * HEADS;
    float* a_dv    = ws + off;          off += (size_t)n * HEADS;
    float* z       = ws + off;          off += (size_t)n * HEADS * HID;

    const int* src = edges;
    const int* dst = edges + E;

    // dtype detect + remap to int32
    k_detect<<<1, 256, 0, stream>>>((const unsigned long long*)ei, E, n, flag);
    k_remap<<<(2 * E + 255) / 256, 256, 0, stream>>>(ei, 2 * E, flag, edges);

    // CSR build
    k_zero<<<(n + 255) / 256, 256, 0, stream>>>(hist, n);
    k_hist<<<(E + 255) / 256, 256, 0, stream>>>(dst, hist, E);
    k_scan1<<<nscan, 256, 0, stream>>>(hist, tmp, partial, n);
    k_scan2<<<1, 256, 0, stream>>>(partial, nscan);
    k_scan3<<<nscan, 256, 0, stream>>>(tmp, partial, hist, row_ptr, cursor, dinv, n);
    k_scatter<<<(E + 255) / 256, 256, 0, stream>>>(src, dst, cursor, colv, E);

    // dense pre-computation
    k_prep<<<1, 256, 0, stream>>>(W_gat, att_s, att_d, w_s, w_d);
    k_xw<<<(n + 15) / 16, 256, 0, stream>>>(x, W_gcn, xw, n);

    // GCN gather + logit dots
    k_gcn<<<(n + 3) / 4, 256, 0, stream>>>(colv, row_ptr, hist, dinv, xw, b_gcn,
                                           w_s, w_d, h1, a_sv, a_dv, n);

    // z projection
    dim3 zg((n + 63) / 64, HEADS);
    k_zgemm<<<zg, 256, 0, stream>>>(h1, W_gat, z, n);

    // fused attention + patch + LN
    k_attn<<<(n + 3) / 4, 256, 0, stream>>>(colv, row_ptr, hist, a_sv, a_dv, z, h1,
                                            W_p, b_p, b_gat, gamma, beta,
                                            (float*)d_out, n);
}

// Round 4
// 415.148 us; speedup vs baseline: 12.4740x; 1.0395x over previous
//
#include <hip/hip_runtime.h>
#include <math.h>

#define IN_DIM 128
#define HID 64
#define HEADS 4
#define NEG_SLOPE 0.2f
#define LN_EPS 1e-5f

// ---------- bf16 helpers ----------
__device__ inline unsigned short f2bf(float f) {
    unsigned u = __float_as_uint(f);
    u += 0x7fffu + ((u >> 16) & 1u);     // round-to-nearest-even
    return (unsigned short)(u >> 16);
}
__device__ inline float bf2f(unsigned short s) {
    return __uint_as_float(((unsigned)s) << 16);
}

// ---------- zero hist + (block 0) sampled dtype detection ----------
__global__ void k_detect_zero(const unsigned long long* ei, int count, int n,
                              int* flag, int* hist) {
    int i = blockIdx.x * blockDim.x + threadIdx.x;
    if (i < n) hist[i] = 0;
    if (blockIdx.x == 0) {
        __shared__ int s_bad;
        if (threadIdx.x == 0) s_bad = 0;
        __syncthreads();
        int lim = count < 4096 ? count : 4096;
        int bad = 0;
        for (int k = threadIdx.x; k < lim; k += 256)
            if (ei[k] >= (unsigned long long)n) bad = 1;
        if (bad) s_bad = 1;      // benign race
        __syncthreads();
        if (threadIdx.x == 0) *flag = s_bad ? 0 : 1;   // 1 = genuine int64
    }
}

// ---------- remap edge_index to int32 + histogram of dst ----------
__global__ void k_remap_hist(const void* ei, int E, const int* flag,
                             int* edges32, int* hist) {
    int i = blockIdx.x * blockDim.x + threadIdx.x;
    if (i >= 2 * E) return;
    int is64 = *flag;
    int v;
    if (is64) v = (int)((const long long*)ei)[i];
    else      v = ((const int*)ei)[i];
    edges32[i] = v;
    if (i >= E) atomicAdd(&hist[v], 1);    // dst half
}

// ---------- CSR scan ----------
__global__ __launch_bounds__(256) void k_scan1(const int* __restrict__ hist,
                                               int* __restrict__ tmp,
                                               int* __restrict__ partial, int n) {
    __shared__ int s[256];
    int t = threadIdx.x, i = blockIdx.x * 256 + t;
    int v = (i < n) ? hist[i] : 0;
    s[t] = v;
    __syncthreads();
    for (int off = 1; off < 256; off <<= 1) {
        int x = (t >= off) ? s[t - off] : 0;
        __syncthreads();
        s[t] += x;
        __syncthreads();
    }
    tmp[i] = s[t] - v;
    if (t == 255) partial[blockIdx.x] = s[255];
}

// scan of block sums (nb <= 256) + folded att-vector prep
__global__ __launch_bounds__(256) void k_scan2_prep(int* partial, int nb,
                                                    const float* __restrict__ Wg,
                                                    const float* __restrict__ att_s,
                                                    const float* __restrict__ att_d,
                                                    float* __restrict__ w_s,
                                                    float* __restrict__ w_d) {
    __shared__ int s[256];
    int t = threadIdx.x;
    int v = (t < nb) ? partial[t] : 0;
    s[t] = v;
    __syncthreads();
    for (int off = 1; off < 256; off <<= 1) {
        int x = (t >= off) ? s[t - off] : 0;
        __syncthreads();
        s[t] += x;
        __syncthreads();
    }
    if (t < nb) partial[t] = s[t] - v;
    // w_s[h,k] = sum_c Wg[k,h,c]*att_s[h,c]
    int h = t >> 6, k = t & 63;
    float ss = 0.0f, sd = 0.0f;
    for (int c = 0; c < HID; c++) {
        float w = Wg[(size_t)k * (HEADS * HID) + h * HID + c];
        ss += w * att_s[h * HID + c];
        sd += w * att_d[h * HID + c];
    }
    w_s[h * HID + k] = ss;
    w_d[h * HID + k] = sd;
}

__global__ void k_scan3(const int* __restrict__ tmp, const int* __restrict__ partial,
                        const int* __restrict__ hist, int* __restrict__ row_ptr,
                        int* __restrict__ cursor, float* __restrict__ dinv, int n) {
    int i = blockIdx.x * blockDim.x + threadIdx.x;
    if (i >= n) return;
    int v = tmp[i] + partial[i >> 8];
    row_ptr[i] = v;
    cursor[i] = v;
    dinv[i] = rsqrtf((float)(hist[i] + 1));   // +1 self-loop
}

__global__ void k_scatter(const int* __restrict__ src, const int* __restrict__ dst,
                          int* __restrict__ cursor, int* __restrict__ col, int E) {
    int i = blockIdx.x * blockDim.x + threadIdx.x;
    if (i >= E) return;
    int pos = atomicAdd(&cursor[dst[i]], 1);
    col[pos] = src[i];
}

// ---------- xws = bf16( (x @ W_gcn) * dinv[row] ) : [n,128]@[128,64] ----------
__global__ __launch_bounds__(256) void k_xw(const float* __restrict__ x,
                                            const float* __restrict__ W,
                                            const float* __restrict__ dinv,
                                            unsigned short* __restrict__ xws, int n) {
    __shared__ float Wl[IN_DIM * HID];   // 32 KB
    __shared__ float xl[16 * IN_DIM];    // 8 KB
    int t = threadIdx.x;
    for (int i = t; i < IN_DIM * HID; i += 256) Wl[i] = W[i];
    int row0 = blockIdx.x * 16;
    for (int i = t; i < 16 * IN_DIM; i += 256) {
        int r = row0 + (i >> 7);
        xl[i] = (r < n) ? x[(size_t)r * IN_DIM + (i & 127)] : 0.0f;
    }
    __syncthreads();
    int c = t & 63, w = t >> 6;
    for (int j = 0; j < 4; j++) {
        int rl = w * 4 + j;
        float acc = 0.0f;
        for (int k = 0; k < IN_DIM; k++) acc += xl[rl * IN_DIM + k] * Wl[k * HID + c];
        int r = row0 + rl;
        if (r < n) xws[(size_t)r * HID + c] = f2bf(acc * dinv[r]);
    }
}

// ---------- GCN via CSR gather (bf16) + fused bias/relu + attention-logit dots ----------
__global__ __launch_bounds__(256) void k_gcn(const int* __restrict__ col,
                                             const int* __restrict__ row_ptr,
                                             const int* __restrict__ hist,
                                             const float* __restrict__ dinv,
                                             const unsigned short* __restrict__ xws,
                                             const float* __restrict__ b,
                                             const float* __restrict__ w_s,
                                             const float* __restrict__ w_d,
                                             float* __restrict__ h1,
                                             float4* __restrict__ a_s,
                                             float4* __restrict__ a_d, int n) {
    int t = threadIdx.x, c = t & 63;
    int d = blockIdx.x * 4 + (t >> 6);
    if (d >= n) return;
    int start = row_ptr[d], cnt = hist[d];
    float acc = bf2f(xws[(size_t)d * HID + c]);       // self term
    for (int k = 0; k < cnt; k++) {
        int s = col[start + k];
        acc += bf2f(xws[(size_t)s * HID + c]);
    }
    float h1c = fmaxf(acc * dinv[d] + b[c], 0.0f);
    h1[(size_t)d * HID + c] = h1c;
    float vs0 = h1c * w_s[c],       vs1 = h1c * w_s[64 + c];
    float vs2 = h1c * w_s[128 + c], vs3 = h1c * w_s[192 + c];
    float vd0 = h1c * w_d[c],       vd1 = h1c * w_d[64 + c];
    float vd2 = h1c * w_d[128 + c], vd3 = h1c * w_d[192 + c];
    for (int o = 32; o > 0; o >>= 1) {
        vs0 += __shfl_xor(vs0, o, 64); vs1 += __shfl_xor(vs1, o, 64);
        vs2 += __shfl_xor(vs2, o, 64); vs3 += __shfl_xor(vs3, o, 64);
        vd0 += __shfl_xor(vd0, o, 64); vd1 += __shfl_xor(vd1, o, 64);
        vd2 += __shfl_xor(vd2, o, 64); vd3 += __shfl_xor(vd3, o, 64);
    }
    if (c == 0) {
        a_s[d] = make_float4(vs0, vs1, vs2, vs3);
        a_d[d] = make_float4(vd0, vd1, vd2, vd3);
    }
}

// ---------- z = bf16(h1 @ W_gat)  (64 rows/block per head) ----------
__global__ __launch_bounds__(256) void k_zgemm(const float* __restrict__ h1,
                                               const float* __restrict__ Wg,
                                               unsigned short* __restrict__ z, int n) {
    __shared__ float Wl[HID * 64];   // 16 KB
    __shared__ float hl[64 * HID];   // 16 KB
    int hh = blockIdx.y;
    int t = threadIdx.x, c = t & 63, w = t >> 6;
    for (int i = t; i < HID * 64; i += 256) {
        int k = i >> 6, cc = i & 63;
        Wl[i] = Wg[(size_t)k * (HEADS * HID) + hh * 64 + cc];
    }
    int row0 = blockIdx.x * 64;
    for (int i = t; i < 64 * HID; i += 256) {
        int r = row0 + (i >> 6);
        hl[i] = (r < n) ? h1[(size_t)r * HID + (i & 63)] : 0.0f;
    }
    __syncthreads();
    for (int j = 0; j < 16; j++) {
        int rl = w * 16 + j;
        float acc = 0.0f;
        for (int k = 0; k < HID; k++) acc += hl[rl * HID + k] * Wl[k * 64 + c];
        int r = row0 + rl;
        if (r < n) z[(size_t)r * (HEADS * HID) + hh * 64 + c] = f2bf(acc);
    }
}

__device__ inline float leaky(float v) { return v > 0.0f ? v : NEG_SLOPE * v; }

// ---------- fused: online-softmax GAT agg (bf16 z) + W_patch + residual + LN ----------
__global__ __launch_bounds__(256) void k_attn(const int* __restrict__ col,
                                              const int* __restrict__ row_ptr,
                                              const int* __restrict__ hist,
                                              const float4* __restrict__ a_s,
                                              const float4* __restrict__ a_d,
                                              const unsigned short* __restrict__ z,
                                              const float* __restrict__ h1,
                                              const float* __restrict__ Wp,
                                              const float* __restrict__ bp,
                                              const float* __restrict__ bg,
                                              const float* __restrict__ gamma,
                                              const float* __restrict__ beta,
                                              float* __restrict__ out, int n) {
    __shared__ float Wl[HID * HID];  // 16 KB
    int t = threadIdx.x;
    for (int i = t; i < HID * HID; i += 256) Wl[i] = Wp[i];
    __syncthreads();
    int c = t & 63;
    int d = blockIdx.x * 4 + (t >> 6);
    if (d >= n) return;
    float4 ad = a_d[d];
    float4 asl = a_s[d];
    // init with self edge
    float m0 = leaky(asl.x + ad.x), m1 = leaky(asl.y + ad.y);
    float m2 = leaky(asl.z + ad.z), m3 = leaky(asl.w + ad.w);
    float l0 = 1.0f, l1 = 1.0f, l2 = 1.0f, l3 = 1.0f;
    const unsigned short* zd = z + (size_t)d * (HEADS * HID);
    float A0 = bf2f(zd[c]), A1 = bf2f(zd[64 + c]);
    float A2 = bf2f(zd[128 + c]), A3 = bf2f(zd[192 + c]);
    int start = row_ptr[d], cnt = hist[d];
    for (int k = 0; k < cnt; k++) {
        int s = col[start + k];
        const unsigned short* zs = z + (size_t)s * (HEADS * HID);
        float4 as_ = a_s[s];
        float e0 = leaky(as_.x + ad.x), e1 = leaky(as_.y + ad.y);
        float e2 = leaky(as_.z + ad.z), e3 = leaky(as_.w + ad.w);
        float z0 = bf2f(zs[c]), z1 = bf2f(zs[64 + c]);
        float z2 = bf2f(zs[128 + c]), z3 = bf2f(zs[192 + c]);
        float nm, sc, w;
        nm = fmaxf(m0, e0); sc = __expf(m0 - nm); w = __expf(e0 - nm);
        l0 = l0 * sc + w; A0 = A0 * sc + w * z0; m0 = nm;
        nm = fmaxf(m1, e1); sc = __expf(m1 - nm); w = __expf(e1 - nm);
        l1 = l1 * sc + w; A1 = A1 * sc + w * z1; m1 = nm;
        nm = fmaxf(m2, e2); sc = __expf(m2 - nm); w = __expf(e2 - nm);
        l2 = l2 * sc + w; A2 = A2 * sc + w * z2; m2 = nm;
        nm = fmaxf(m3, e3); sc = __expf(m3 - nm); w = __expf(e3 - nm);
        l3 = l3 * sc + w; A3 = A3 * sc + w * z3; m3 = nm;
    }
    float v = A0 / l0 + A1 / l1 + A2 / l2 + A3 / l3;
    float h2 = fmaxf(0.25f * v + bg[c], 0.0f);
    float h1c = h1[(size_t)d * HID + c];
    float hp = bp[c];
    for (int k = 0; k < HID; k++) hp += __shfl(h1c, k, 64) * Wl[k * HID + c];
    float h = h1c + h2 + hp;
    float s1 = h, s2 = h * h;
    for (int o = 32; o > 0; o >>= 1) {
        s1 += __shfl_xor(s1, o, 64);
        s2 += __shfl_xor(s2, o, 64);
    }
    float mu = s1 * (1.0f / 64.0f);
    float var = s2 * (1.0f / 64.0f) - mu * mu;
    out[(size_t)d * HID + c] = (h - mu) * rsqrtf(var + LN_EPS) * gamma[c] + beta[c];
}

extern "C" void kernel_launch(void* const* d_in, const int* in_sizes, int n_in,
                              void* d_out, int out_size, void* d_ws, size_t ws_size,
                              hipStream_t stream) {
    int n = in_sizes[0] / IN_DIM;
    int E = in_sizes[1] / 2;

    const float* x     = (const float*)d_in[0];
    const void*  ei    = d_in[1];
    const float* W_gcn = (const float*)d_in[2];
    const float* b_gcn = (const float*)d_in[3];
    const float* W_gat = (const float*)d_in[4];
    const float* att_s = (const float*)d_in[5];
    const float* att_d = (const float*)d_in[6];
    const float* b_gat = (const float*)d_in[7];
    const float* W_p   = (const float*)d_in[8];
    const float* b_p   = (const float*)d_in[9];
    const float* gamma = (const float*)d_in[10];
    const float* beta  = (const float*)d_in[11];

    int n_pad = ((n + 255) / 256) * 256;
    int nscan = n_pad / 256;                 // must be <= 256

    float* ws = (float*)d_ws;
    size_t off = 0;
    int*   flag    = (int*)(ws + off);  off += 4;               // padded for alignment
    int*   edges   = (int*)(ws + off);  off += (size_t)2 * E;
    int*   hist    = (int*)(ws + off);  off += n;
    int*   row_ptr = (int*)(ws + off);  off += n;
    int*   cursor  = (int*)(ws + off);  off += n;
    int*   tmp     = (int*)(ws + off);  off += n_pad;
    int*   partial = (int*)(ws + off);  off += 256;
    int*   colv    = (int*)(ws + off);  off += E;
    float* dinv    = ws + off;          off += n;
    float* w_s     = ws + off;          off += HEADS * HID;
    float* w_d     = ws + off;          off += HEADS * HID;
    off = (off + 3) & ~(size_t)3;
    unsigned short* xws = (unsigned short*)(ws + off); off += (size_t)n * HID / 2;
    float* h1      = ws + off;          off += (size_t)n * HID;
    off = (off + 3) & ~(size_t)3;
    float4* a_sv   = (float4*)(ws + off); off += (size_t)n * 4;
    float4* a_dv   = (float4*)(ws + off); off += (size_t)n * 4;
    unsigned short* z = (unsigned short*)(ws + off); off += (size_t)n * HEADS * HID / 2;

    const int* src = edges;
    const int* dst = edges + E;

    // detect dtype (block 0) + zero hist
    k_detect_zero<<<(n + 255) / 256, 256, 0, stream>>>(
        (const unsigned long long*)ei, E, n, flag, hist);
    // remap to int32 + dst histogram
    k_remap_hist<<<(2 * E + 255) / 256, 256, 0, stream>>>(ei, E, flag, edges, hist);

    // CSR scan + scatter (+ folded att prep)
    k_scan1<<<nscan, 256, 0, stream>>>(hist, tmp, partial, n);
    k_scan2_prep<<<1, 256, 0, stream>>>(partial, nscan, W_gat, att_s, att_d, w_s, w_d);
    k_scan3<<<nscan, 256, 0, stream>>>(tmp, partial, hist, row_ptr, cursor, dinv, n);
    k_scatter<<<(E + 255) / 256, 256, 0, stream>>>(src, dst, cursor, colv, E);

    // dense GCN projection (bf16, pre-scaled by dinv)
    k_xw<<<(n + 15) / 16, 256, 0, stream>>>(x, W_gcn, dinv, xws, n);

    // GCN gather + logit dots
    k_gcn<<<(n + 3) / 4, 256, 0, stream>>>(colv, row_ptr, hist, dinv, xws, b_gcn,
                                           w_s, w_d, h1, a_sv, a_dv, n);

    // z projection (bf16 out)
    dim3 zg((n + 63) / 64, HEADS);
    k_zgemm<<<zg, 256, 0, stream>>>(h1, W_gat, z, n);

    // fused attention + patch + LN
    k_attn<<<(n + 3) / 4, 256, 0, stream>>>(colv, row_ptr, hist, a_sv, a_dv, z, h1,
                                            W_p, b_p, b_gat, gamma, beta,
                                            (float*)d_out, n);
}